// Round 1
// baseline (1115.894 us; speedup 1.0000x reference)
//
#include <hip/hip_runtime.h>

#define NN 50000
#define NE 800000
#define INF 128
#define HID 64
#define HEADS 4
#define HD 256      // HEADS*HID
#define ACT 16
#define NEG_SLOPE 0.2f

// ---------------- generic fp32 GEMM: C[M,N] = A[M,K] @ B', 64x64 tile, 4x4/thread ---
// B element (k, col) = B[k*ldb + (col & 63) + (col>>6)*panel_stride]
__global__ __launch_bounds__(256) void gemm_kernel(
    const float* __restrict__ A, const float* __restrict__ B, float* __restrict__ C,
    int M, int N, int K, int ldb, int panel_stride)
{
    __shared__ float As[16][64];   // As[k][m]
    __shared__ float Bs[16][64];   // Bs[k][n]
    const int tid = threadIdx.x;
    const int bx = blockIdx.x, by = blockIdx.y;
    const int row0 = by * 64, col0 = bx * 64;
    const int tm = (tid >> 4) << 2;      // 0..60
    const int tn = (tid & 15) << 2;      // 0..60
    float acc[4][4] = {};

    const int arow = tid >> 2;           // 0..63
    const int ak   = (tid & 3) << 2;     // 0,4,8,12
    const int bk   = tid >> 4;           // 0..15
    const int bc   = (tid & 15) << 2;    // 0..60
    const int grow = row0 + arow;
    const float* Abase = (grow < M) ? (A + (size_t)grow * K + ak) : nullptr;
    const float* Bbase = B + (size_t)(col0 >> 6) * panel_stride + bc;

    for (int k0 = 0; k0 < K; k0 += 16) {
        float4 av = make_float4(0.f, 0.f, 0.f, 0.f);
        if (Abase) av = *(const float4*)(Abase + k0);
        As[ak + 0][arow] = av.x; As[ak + 1][arow] = av.y;
        As[ak + 2][arow] = av.z; As[ak + 3][arow] = av.w;
        float4 bv = *(const float4*)(Bbase + (size_t)(k0 + bk) * ldb);
        *(float4*)&Bs[bk][bc] = bv;
        __syncthreads();
#pragma unroll
        for (int k = 0; k < 16; ++k) {
            const float4 a = *(const float4*)&As[k][tm];
            const float4 b = *(const float4*)&Bs[k][tn];
            acc[0][0] += a.x * b.x; acc[0][1] += a.x * b.y; acc[0][2] += a.x * b.z; acc[0][3] += a.x * b.w;
            acc[1][0] += a.y * b.x; acc[1][1] += a.y * b.y; acc[1][2] += a.y * b.z; acc[1][3] += a.y * b.w;
            acc[2][0] += a.z * b.x; acc[2][1] += a.z * b.y; acc[2][2] += a.z * b.z; acc[2][3] += a.z * b.w;
            acc[3][0] += a.w * b.x; acc[3][1] += a.w * b.y; acc[3][2] += a.w * b.z; acc[3][3] += a.w * b.w;
        }
        __syncthreads();
    }
#pragma unroll
    for (int r = 0; r < 4; ++r) {
        int gr = row0 + tm + r;
        if (gr < M)
            *(float4*)(C + (size_t)gr * N + col0 + tn) =
                make_float4(acc[r][0], acc[r][1], acc[r][2], acc[r][3]);
    }
}

// ---------------- el/er: per node, wave h reduces head h --------------------------
__global__ __launch_bounds__(256) void elr_kernel(const float* __restrict__ h0,
    const float* __restrict__ attn_l, const float* __restrict__ attn_r,
    float* __restrict__ elr /* [N][8]: el[0..3], er[4..7] */)
{
    const int n = blockIdx.x;
    const int t = threadIdx.x;
    const float v = h0[(size_t)n * HD + t];
    float l = v * attn_l[t];
    float r = v * attn_r[t];
#pragma unroll
    for (int off = 32; off; off >>= 1) { l += __shfl_xor(l, off); r += __shfl_xor(r, off); }
    if ((t & 63) == 0) {
        const int h = t >> 6;
        elr[n * 8 + h]     = l;
        elr[n * 8 + 4 + h] = r;
    }
}

// ---------------- per-edge: ex = exp(leaky_relu(el[s]+er[d])), z += ex ------------
// (segment-max skipped: alpha is invariant to the max shift and |e| is small)
__global__ __launch_bounds__(256) void edge_ex_kernel(const int* __restrict__ src,
    const int* __restrict__ dst, const float* __restrict__ elr,
    float* __restrict__ ex, float* __restrict__ z)
{
    const int e = blockIdx.x * 256 + threadIdx.x;
    if (e >= NE) return;
    const int s = src[e], d = dst[e];
    const float4 el = *(const float4*)(elr + (size_t)s * 8);
    const float4 er = *(const float4*)(elr + (size_t)d * 8 + 4);
    float vals[4] = { el.x + er.x, el.y + er.y, el.z + er.z, el.w + er.w };
    float exv[4];
#pragma unroll
    for (int h = 0; h < 4; ++h) {
        float x = vals[h];
        x = x > 0.f ? x : NEG_SLOPE * x;
        exv[h] = expf(x);
        atomicAdd(z + (size_t)d * 4 + h, exv[h]);
    }
    *(float4*)(ex + (size_t)e * 4) = make_float4(exv[0], exv[1], exv[2], exv[3]);
}

// ---------------- aggregation: rst[dst] += alpha * h0[src], one wave per edge -----
__global__ __launch_bounds__(256) void aggregate_kernel(const int* __restrict__ src,
    const int* __restrict__ dst, const float* __restrict__ ex, const float* __restrict__ z,
    const float* __restrict__ h0, float* __restrict__ rst)
{
    const int wid = threadIdx.x >> 6;
    const int lane = threadIdx.x & 63;
    const int e = blockIdx.x * 4 + wid;
    const int s = src[e], d = dst[e];
    const float4 x4 = *(const float4*)(ex + (size_t)e * 4);
    const float4 z4 = *(const float4*)(z + (size_t)d * 4);
    const float a0 = x4.x / z4.x, a1 = x4.y / z4.y, a2 = x4.z / z4.z, a3 = x4.w / z4.w;
    const float* hs = h0 + (size_t)s * HD;
    float* rd = rst + (size_t)d * HD;
    atomicAdd(rd + lane,        a0 * hs[lane]);
    atomicAdd(rd + 64 + lane,   a1 * hs[64 + lane]);
    atomicAdd(rd + 128 + lane,  a2 * hs[128 + lane]);
    atomicAdd(rd + 192 + lane,  a3 * hs[192 + lane]);
}

// ---------------- elu(rst + bias) in place + column sums for graph mean ----------
__global__ __launch_bounds__(256) void elu_mean_kernel(float* __restrict__ rst,
    const float* __restrict__ gat_bias, float* __restrict__ gacc)
{
    const int t = threadIdx.x;
    const float b = gat_bias[t];
    float local = 0.f;
    for (int n = blockIdx.x; n < NN; n += gridDim.x) {
        float v = rst[(size_t)n * HD + t] + b;
        v = v > 0.f ? v : expm1f(v);
        rst[(size_t)n * HD + t] = v;
        local += v;
    }
    atomicAdd(gacc + t, local);
}

// ---------------- per-edge actor MLP: relu(p[s]+q[d]+b1) @ w2 + b2 ----------------
__global__ __launch_bounds__(256) void edge_mlp_kernel(const int* __restrict__ src,
    const int* __restrict__ dst, const float* __restrict__ pq,
    const float* __restrict__ a_b1, const float* __restrict__ a_w2,
    const float* __restrict__ a_b2, float* __restrict__ out)
{
    __shared__ float W2[HID * ACT];
    __shared__ float B1[HID];
    __shared__ float B2[ACT];
    const int tid = threadIdx.x;
    for (int i = tid; i < HID * ACT; i += 256) W2[i] = a_w2[i];
    if (tid < HID) B1[tid] = a_b1[tid];
    if (tid < ACT) B2[tid] = a_b2[tid];
    __syncthreads();
    const int e = blockIdx.x * 256 + tid;
    if (e >= NE) return;
    const int s = src[e], d = dst[e];
    const float4* P = (const float4*)(pq + (size_t)s * 128);
    const float4* Q = (const float4*)(pq + (size_t)d * 128 + 64);
    float t64[64];
#pragma unroll
    for (int j4 = 0; j4 < 16; ++j4) {
        const float4 p = P[j4];
        const float4 q = Q[j4];
        const float4 b = *(const float4*)&B1[j4 * 4];
        t64[j4 * 4 + 0] = fmaxf(p.x + q.x + b.x, 0.f);
        t64[j4 * 4 + 1] = fmaxf(p.y + q.y + b.y, 0.f);
        t64[j4 * 4 + 2] = fmaxf(p.z + q.z + b.z, 0.f);
        t64[j4 * 4 + 3] = fmaxf(p.w + q.w + b.w, 0.f);
    }
    float4 acc0 = *(const float4*)&B2[0];
    float4 acc1 = *(const float4*)&B2[4];
    float4 acc2 = *(const float4*)&B2[8];
    float4 acc3 = *(const float4*)&B2[12];
#pragma unroll
    for (int j = 0; j < 64; ++j) {
        const float tv = t64[j];
        const float4 w0 = *(const float4*)&W2[j * 16 + 0];
        const float4 w1 = *(const float4*)&W2[j * 16 + 4];
        const float4 w2 = *(const float4*)&W2[j * 16 + 8];
        const float4 w3 = *(const float4*)&W2[j * 16 + 12];
        acc0.x += tv * w0.x; acc0.y += tv * w0.y; acc0.z += tv * w0.z; acc0.w += tv * w0.w;
        acc1.x += tv * w1.x; acc1.y += tv * w1.y; acc1.z += tv * w1.z; acc1.w += tv * w1.w;
        acc2.x += tv * w2.x; acc2.y += tv * w2.y; acc2.z += tv * w2.z; acc2.w += tv * w2.w;
        acc3.x += tv * w3.x; acc3.y += tv * w3.y; acc3.z += tv * w3.z; acc3.w += tv * w3.w;
    }
    float* o = out + (size_t)e * 16;
    *(float4*)(o + 0)  = acc0;
    *(float4*)(o + 4)  = acc1;
    *(float4*)(o + 8)  = acc2;
    *(float4*)(o + 12) = acc3;
}

// ---------------- critic: relu(mean(h) @ c_w1 + c_b1) @ c_w2 + c_b2 --------------
__global__ __launch_bounds__(256) void critic_kernel(const float* __restrict__ gacc,
    const float* __restrict__ c_w1, const float* __restrict__ c_b1,
    const float* __restrict__ c_w2, const float* __restrict__ c_b2,
    float* __restrict__ out)
{
    __shared__ float g[HD];
    __shared__ float t1[HID];
    const int t = threadIdx.x;
    g[t] = gacc[t] * (1.0f / (float)NN);
    __syncthreads();
    if (t < HID) {
        float s = c_b1[t];
        for (int c = 0; c < HD; ++c) s += g[c] * c_w1[c * HID + t];
        t1[t] = fmaxf(s, 0.f);
    }
    __syncthreads();
    if (t == 0) {
        float s = c_b2[0];
        for (int j = 0; j < HID; ++j) s += t1[j] * c_w2[j];
        out[0] = s;
    }
}

extern "C" void kernel_launch(void* const* d_in, const int* in_sizes, int n_in,
                              void* d_out, int out_size, void* d_ws, size_t ws_size,
                              hipStream_t stream)
{
    const float* x      = (const float*)d_in[0];
    const int*   src    = (const int*)d_in[1];
    const int*   dst    = (const int*)d_in[2];
    const float* fc_w   = (const float*)d_in[3];
    const float* attn_l = (const float*)d_in[4];
    const float* attn_r = (const float*)d_in[5];
    const float* gat_b  = (const float*)d_in[6];
    const float* a_w1   = (const float*)d_in[7];
    const float* a_b1   = (const float*)d_in[8];
    const float* a_w2   = (const float*)d_in[9];
    const float* a_b2   = (const float*)d_in[10];
    const float* c_w1   = (const float*)d_in[11];
    const float* c_b1   = (const float*)d_in[12];
    const float* c_w2   = (const float*)d_in[13];
    const float* c_b2   = (const float*)d_in[14];
    float* out = (float*)d_out;

    float* ws   = (float*)d_ws;
    float* h0   = ws;                    // 12,800,000 floats (reused as pq later)
    float* elr  = h0  + 12800000;        //    400,000
    float* ex   = elr + 400000;          //  3,200,000
    float* z    = ex  + 3200000;         //    200,000
    float* rst  = z   + 200000;          // 12,800,000
    float* gacc = rst + 12800000;        //        256
    float* pq   = h0;                    // p|q packed [N][128]

    hipMemsetAsync(z,    0, 200000   * sizeof(float), stream);
    hipMemsetAsync(rst,  0, 12800000 * sizeof(float), stream);
    hipMemsetAsync(gacc, 0, 256      * sizeof(float), stream);

    dim3 blk(256);
    // h0 = X @ fc_w : [50000,128]@[128,256]
    gemm_kernel<<<dim3(4, 782), blk, 0, stream>>>(x, fc_w, h0, NN, HD, INF, HD, 64);
    elr_kernel<<<dim3(NN), blk, 0, stream>>>(h0, attn_l, attn_r, elr);
    edge_ex_kernel<<<dim3(3125), blk, 0, stream>>>(src, dst, elr, ex, z);
    aggregate_kernel<<<dim3(NE / 4), blk, 0, stream>>>(src, dst, ex, z, h0, rst);
    elu_mean_kernel<<<dim3(512), blk, 0, stream>>>(rst, gat_b, gacc);
    // pq = h @ [a_w1_top | a_w1_bot] : [50000,256]@[256,128] (panelized B)
    gemm_kernel<<<dim3(2, 782), blk, 0, stream>>>(rst, a_w1, pq, NN, 128, HD, HID, HD * HID);
    edge_mlp_kernel<<<dim3(3125), blk, 0, stream>>>(src, dst, pq, a_b1, a_w2, a_b2, out);
    critic_kernel<<<dim3(1), blk, 0, stream>>>(gacc, c_w1, c_b1, c_w2, c_b2,
                                               out + (size_t)NE * ACT);
}

// Round 2
// 585.581 us; speedup vs baseline: 1.9056x; 1.9056x over previous
//
#include <hip/hip_runtime.h>

#define NN 50000
#define NE 800000
#define INF 128
#define HID 64
#define HEADS 4
#define HD 256      // HEADS*HID
#define ACT 16
#define NEG_SLOPE 0.2f

// ---------------- generic fp32 GEMM: C[M,N] = A[M,K] @ B', 64x64 tile, 4x4/thread ---
// B element (k, col) = B[k*ldb + (col & 63) + (col>>6)*panel_stride]
__global__ __launch_bounds__(256) void gemm_kernel(
    const float* __restrict__ A, const float* __restrict__ B, float* __restrict__ C,
    int M, int N, int K, int ldb, int panel_stride)
{
    __shared__ float As[16][64];   // As[k][m]
    __shared__ float Bs[16][64];   // Bs[k][n]
    const int tid = threadIdx.x;
    const int bx = blockIdx.x, by = blockIdx.y;
    const int row0 = by * 64, col0 = bx * 64;
    const int tm = (tid >> 4) << 2;      // 0..60
    const int tn = (tid & 15) << 2;      // 0..60
    float acc[4][4] = {};

    const int arow = tid >> 2;           // 0..63
    const int ak   = (tid & 3) << 2;     // 0,4,8,12
    const int bk   = tid >> 4;           // 0..15
    const int bc   = (tid & 15) << 2;    // 0..60
    const int grow = row0 + arow;
    const float* Abase = (grow < M) ? (A + (size_t)grow * K + ak) : nullptr;
    const float* Bbase = B + (size_t)(col0 >> 6) * panel_stride + bc;

    for (int k0 = 0; k0 < K; k0 += 16) {
        float4 av = make_float4(0.f, 0.f, 0.f, 0.f);
        if (Abase) av = *(const float4*)(Abase + k0);
        As[ak + 0][arow] = av.x; As[ak + 1][arow] = av.y;
        As[ak + 2][arow] = av.z; As[ak + 3][arow] = av.w;
        float4 bv = *(const float4*)(Bbase + (size_t)(k0 + bk) * ldb);
        *(float4*)&Bs[bk][bc] = bv;
        __syncthreads();
#pragma unroll
        for (int k = 0; k < 16; ++k) {
            const float4 a = *(const float4*)&As[k][tm];
            const float4 b = *(const float4*)&Bs[k][tn];
            acc[0][0] += a.x * b.x; acc[0][1] += a.x * b.y; acc[0][2] += a.x * b.z; acc[0][3] += a.x * b.w;
            acc[1][0] += a.y * b.x; acc[1][1] += a.y * b.y; acc[1][2] += a.y * b.z; acc[1][3] += a.y * b.w;
            acc[2][0] += a.z * b.x; acc[2][1] += a.z * b.y; acc[2][2] += a.z * b.z; acc[2][3] += a.z * b.w;
            acc[3][0] += a.w * b.x; acc[3][1] += a.w * b.y; acc[3][2] += a.w * b.z; acc[3][3] += a.w * b.w;
        }
        __syncthreads();
    }
#pragma unroll
    for (int r = 0; r < 4; ++r) {
        int gr = row0 + tm + r;
        if (gr < M)
            *(float4*)(C + (size_t)gr * N + col0 + tn) =
                make_float4(acc[r][0], acc[r][1], acc[r][2], acc[r][3]);
    }
}

// ---------------- el/er: per node, wave h reduces head h --------------------------
__global__ __launch_bounds__(256) void elr_kernel(const float* __restrict__ h0,
    const float* __restrict__ attn_l, const float* __restrict__ attn_r,
    float* __restrict__ elr /* [N][8]: el[0..3], er[4..7] */)
{
    const int n = blockIdx.x;
    const int t = threadIdx.x;
    const float v = h0[(size_t)n * HD + t];
    float l = v * attn_l[t];
    float r = v * attn_r[t];
#pragma unroll
    for (int off = 32; off; off >>= 1) { l += __shfl_xor(l, off); r += __shfl_xor(r, off); }
    if ((t & 63) == 0) {
        const int h = t >> 6;
        elr[n * 8 + h]     = l;
        elr[n * 8 + 4 + h] = r;
    }
}

// ---------------- CSR build -------------------------------------------------------
__global__ __launch_bounds__(256) void deg_kernel(const int* __restrict__ dst,
                                                  int* __restrict__ deg)
{
    const int e = blockIdx.x * 256 + threadIdx.x;
    if (e < NE) atomicAdd(&deg[dst[e]], 1);
}

__global__ __launch_bounds__(256) void scan_block_kernel(const int* __restrict__ deg,
    int* __restrict__ excl, int* __restrict__ blocksum)
{
    __shared__ int tmp[256];
    const int t = threadIdx.x;
    const int i = blockIdx.x * 256 + t;
    const int v = (i < NN) ? deg[i] : 0;
    tmp[t] = v;
    __syncthreads();
    for (int off = 1; off < 256; off <<= 1) {
        int x = (t >= off) ? tmp[t - off] : 0;
        __syncthreads();
        tmp[t] += x;
        __syncthreads();
    }
    if (i < NN) excl[i] = tmp[t] - v;
    if (t == 255) blocksum[blockIdx.x] = tmp[255];
}

__global__ void scan_top_kernel(int* __restrict__ blocksum, int nb)
{
    const int lane = threadIdx.x;   // 64 threads
    int carry = 0;
    for (int base = 0; base < nb; base += 64) {
        const int i = base + lane;
        const int v = (i < nb) ? blocksum[i] : 0;
        int incl = v;
#pragma unroll
        for (int off = 1; off < 64; off <<= 1) {
            int x = __shfl_up(incl, off);
            if (lane >= off) incl += x;
        }
        if (i < nb) blocksum[i] = carry + incl - v;
        carry += __shfl(incl, 63);
    }
}

__global__ __launch_bounds__(256) void scan_add_kernel(const int* __restrict__ excl,
    const int* __restrict__ blocksum, int* __restrict__ rowptr, int* __restrict__ wptr)
{
    const int i = blockIdx.x * 256 + threadIdx.x;
    if (i < NN) {
        const int v = excl[i] + blocksum[blockIdx.x];
        rowptr[i] = v;
        wptr[i] = v;
    }
    if (i == 0) rowptr[NN] = NE;
}

__global__ __launch_bounds__(256) void scatter_kernel(const int* __restrict__ src,
    const int* __restrict__ dst, int* __restrict__ wptr, int* __restrict__ esrc)
{
    const int e = blockIdx.x * 256 + threadIdx.x;
    if (e < NE) {
        const int p = atomicAdd(&wptr[dst[e]], 1);
        esrc[p] = src[e];
    }
}

// ---------------- gather aggregation: rst[d] = elu( (Σ ex·h0[s]) / Σ ex + bias ) --
__global__ __launch_bounds__(256) void aggregate_csr_kernel(
    const int* __restrict__ rowptr, const int* __restrict__ esrc,
    const float* __restrict__ elr, const float* __restrict__ h0,
    const float* __restrict__ gat_bias, float* __restrict__ rst)
{
    const int d = blockIdx.x;
    const int t = threadIdx.x;      // feature index 0..255
    const int h = t >> 6;           // head
    const int start = rowptr[d], end = rowptr[d + 1];
    const float erd = elr[(size_t)d * 8 + 4 + h];
    float acc = 0.f, zsum = 0.f;
    for (int i = start; i < end; ++i) {
        const int s = esrc[i];
        float x = elr[(size_t)s * 8 + h] + erd;
        x = x > 0.f ? x : NEG_SLOPE * x;
        const float ex = expf(x);
        zsum += ex;
        acc += ex * h0[(size_t)s * HD + t];
    }
    float v = (end > start) ? (acc / zsum) : 0.f;
    v += gat_bias[t];
    v = v > 0.f ? v : expm1f(v);
    rst[(size_t)d * HD + t] = v;
}

// ---------------- column sums for graph mean --------------------------------------
__global__ __launch_bounds__(256) void mean_kernel(const float* __restrict__ rst,
                                                   float* __restrict__ gacc)
{
    const int t = threadIdx.x;
    float local = 0.f;
    for (int n = blockIdx.x; n < NN; n += gridDim.x)
        local += rst[(size_t)n * HD + t];
    atomicAdd(gacc + t, local);
}

// ---------------- per-edge actor MLP: relu(p[s]+q[d]+b1) @ w2 + b2 ----------------
__global__ __launch_bounds__(256) void edge_mlp_kernel(const int* __restrict__ src,
    const int* __restrict__ dst, const float* __restrict__ pq,
    const float* __restrict__ a_b1, const float* __restrict__ a_w2,
    const float* __restrict__ a_b2, float* __restrict__ out)
{
    __shared__ float W2[HID * ACT];
    __shared__ float B1[HID];
    __shared__ float B2[ACT];
    const int tid = threadIdx.x;
    for (int i = tid; i < HID * ACT; i += 256) W2[i] = a_w2[i];
    if (tid < HID) B1[tid] = a_b1[tid];
    if (tid < ACT) B2[tid] = a_b2[tid];
    __syncthreads();
    const int e = blockIdx.x * 256 + tid;
    if (e >= NE) return;
    const int s = src[e], d = dst[e];
    const float4* P = (const float4*)(pq + (size_t)s * 128);
    const float4* Q = (const float4*)(pq + (size_t)d * 128 + 64);
    float t64[64];
#pragma unroll
    for (int j4 = 0; j4 < 16; ++j4) {
        const float4 p = P[j4];
        const float4 q = Q[j4];
        const float4 b = *(const float4*)&B1[j4 * 4];
        t64[j4 * 4 + 0] = fmaxf(p.x + q.x + b.x, 0.f);
        t64[j4 * 4 + 1] = fmaxf(p.y + q.y + b.y, 0.f);
        t64[j4 * 4 + 2] = fmaxf(p.z + q.z + b.z, 0.f);
        t64[j4 * 4 + 3] = fmaxf(p.w + q.w + b.w, 0.f);
    }
    float4 acc0 = *(const float4*)&B2[0];
    float4 acc1 = *(const float4*)&B2[4];
    float4 acc2 = *(const float4*)&B2[8];
    float4 acc3 = *(const float4*)&B2[12];
#pragma unroll
    for (int j = 0; j < 64; ++j) {
        const float tv = t64[j];
        const float4 w0 = *(const float4*)&W2[j * 16 + 0];
        const float4 w1 = *(const float4*)&W2[j * 16 + 4];
        const float4 w2 = *(const float4*)&W2[j * 16 + 8];
        const float4 w3 = *(const float4*)&W2[j * 16 + 12];
        acc0.x += tv * w0.x; acc0.y += tv * w0.y; acc0.z += tv * w0.z; acc0.w += tv * w0.w;
        acc1.x += tv * w1.x; acc1.y += tv * w1.y; acc1.z += tv * w1.z; acc1.w += tv * w1.w;
        acc2.x += tv * w2.x; acc2.y += tv * w2.y; acc2.z += tv * w2.z; acc2.w += tv * w2.w;
        acc3.x += tv * w3.x; acc3.y += tv * w3.y; acc3.z += tv * w3.z; acc3.w += tv * w3.w;
    }
    float* o = out + (size_t)e * 16;
    *(float4*)(o + 0)  = acc0;
    *(float4*)(o + 4)  = acc1;
    *(float4*)(o + 8)  = acc2;
    *(float4*)(o + 12) = acc3;
}

// ---------------- critic: relu(mean(h) @ c_w1 + c_b1) @ c_w2 + c_b2 --------------
__global__ __launch_bounds__(256) void critic_kernel(const float* __restrict__ gacc,
    const float* __restrict__ c_w1, const float* __restrict__ c_b1,
    const float* __restrict__ c_w2, const float* __restrict__ c_b2,
    float* __restrict__ out)
{
    __shared__ float g[HD];
    __shared__ float t1[HID];
    const int t = threadIdx.x;
    g[t] = gacc[t] * (1.0f / (float)NN);
    __syncthreads();
    if (t < HID) {
        float s = c_b1[t];
        for (int c = 0; c < HD; ++c) s += g[c] * c_w1[c * HID + t];
        t1[t] = fmaxf(s, 0.f);
    }
    __syncthreads();
    if (t == 0) {
        float s = c_b2[0];
        for (int j = 0; j < HID; ++j) s += t1[j] * c_w2[j];
        out[0] = s;
    }
}

extern "C" void kernel_launch(void* const* d_in, const int* in_sizes, int n_in,
                              void* d_out, int out_size, void* d_ws, size_t ws_size,
                              hipStream_t stream)
{
    const float* x      = (const float*)d_in[0];
    const int*   src    = (const int*)d_in[1];
    const int*   dst    = (const int*)d_in[2];
    const float* fc_w   = (const float*)d_in[3];
    const float* attn_l = (const float*)d_in[4];
    const float* attn_r = (const float*)d_in[5];
    const float* gat_b  = (const float*)d_in[6];
    const float* a_w1   = (const float*)d_in[7];
    const float* a_b1   = (const float*)d_in[8];
    const float* a_w2   = (const float*)d_in[9];
    const float* a_b2   = (const float*)d_in[10];
    const float* c_w1   = (const float*)d_in[11];
    const float* c_b1   = (const float*)d_in[12];
    const float* c_w2   = (const float*)d_in[13];
    const float* c_b2   = (const float*)d_in[14];
    float* out = (float*)d_out;

    float* ws   = (float*)d_ws;
    float* h0   = ws;                    // 12,800,000 (reused as pq later)
    float* elr  = h0  + 12800000;        //    400,000
    float* rst  = elr + 400000;          // 12,800,000
    float* gacc = rst + 12800000;        //        256
    int* deg      = (int*)(gacc + 256);  //     50,000
    int* excl     = deg + 50000;         //     50,000
    int* blocksum = excl + 50000;        //        256
    int* rowptr   = blocksum + 256;      //     50,001
    int* wptr     = rowptr + 50001;      //     50,000
    int* esrc     = wptr + 50000;        //    800,000
    float* pq = h0;

    hipMemsetAsync(deg,  0, 50000 * sizeof(int), stream);
    hipMemsetAsync(gacc, 0, 256 * sizeof(float), stream);

    dim3 blk(256);
    const int NB = (NN + 255) / 256;  // 196
    // CSR build
    deg_kernel<<<dim3(3125), blk, 0, stream>>>(dst, deg);
    scan_block_kernel<<<dim3(NB), blk, 0, stream>>>(deg, excl, blocksum);
    scan_top_kernel<<<dim3(1), dim3(64), 0, stream>>>(blocksum, NB);
    scan_add_kernel<<<dim3(NB), blk, 0, stream>>>(excl, blocksum, rowptr, wptr);
    scatter_kernel<<<dim3(3125), blk, 0, stream>>>(src, dst, wptr, esrc);
    // h0 = X @ fc_w : [50000,128]@[128,256]
    gemm_kernel<<<dim3(4, 782), blk, 0, stream>>>(x, fc_w, h0, NN, HD, INF, HD, 64);
    elr_kernel<<<dim3(NN), blk, 0, stream>>>(h0, attn_l, attn_r, elr);
    // gather-side aggregation (fused ex/z/bias/elu)
    aggregate_csr_kernel<<<dim3(NN), blk, 0, stream>>>(rowptr, esrc, elr, h0, gat_b, rst);
    mean_kernel<<<dim3(512), blk, 0, stream>>>(rst, gacc);
    // pq = h @ [a_w1_top | a_w1_bot] : [50000,256]@[256,128] (panelized B)
    gemm_kernel<<<dim3(2, 782), blk, 0, stream>>>(rst, a_w1, pq, NN, 128, HD, HID, HD * HID);
    edge_mlp_kernel<<<dim3(3125), blk, 0, stream>>>(src, dst, pq, a_b1, a_w2, a_b2, out);
    critic_kernel<<<dim3(1), blk, 0, stream>>>(gacc, c_w1, c_b1, c_w2, c_b2,
                                               out + (size_t)NE * ACT);
}

// Round 3
// 319.889 us; speedup vs baseline: 3.4884x; 1.8306x over previous
//
#include <hip/hip_runtime.h>

#define NN 50000
#define NE 800000
#define INF 128
#define HID 64
#define HEADS 4
#define HD 256      // HEADS*HID
#define ACT 16
#define NEG_SLOPE 0.2f

typedef short bf8 __attribute__((ext_vector_type(8)));   // 8 bf16 (bit pattern in shorts)
typedef float f4 __attribute__((ext_vector_type(4)));
typedef unsigned short u16;

__device__ __forceinline__ u16 f2bf(float f) {           // RNE fp32 -> bf16
    unsigned u = __builtin_bit_cast(unsigned, f);
    u += 0x7fffu + ((u >> 16) & 1u);
    return (u16)(u >> 16);
}
__device__ __forceinline__ float bf2f(u16 h) {
    return __builtin_bit_cast(float, (unsigned)h << 16);
}

// ---------------- weight conversion to swizzled bf16 frag layout ------------------
// frag layout: lane l holds element (k = kc*32 + (l>>4)*8 + j, col = ct*16 + (l&15))
__global__ __launch_bounds__(256) void convw_kernel(const float* __restrict__ fc_w,
    const float* __restrict__ a_w1, const float* __restrict__ a_w2,
    u16* __restrict__ Bsw1, u16* __restrict__ Bsw2, u16* __restrict__ w2sw)
{
    const int idx = blockIdx.x * 256 + threadIdx.x;
    if (idx < 32768) {                       // fc_w [128][256] -> 16ct x 4kc
        int j = idx & 7, l = (idx >> 3) & 63, q = idx >> 9;
        int kc = q & 3, ct = q >> 2;
        int k = kc * 32 + ((l >> 4) << 3) + j, col = (ct << 4) + (l & 15);
        Bsw1[idx] = f2bf(fc_w[k * 256 + col]);
    } else if (idx < 65536) {                // a_w1 [512][64] -> eff [256][128], 8ct x 8kc
        int o = idx - 32768;
        int j = o & 7, l = (o >> 3) & 63, q = o >> 9;
        int kc = q & 7, ct = q >> 3;
        int k = kc * 32 + ((l >> 4) << 3) + j, col = (ct << 4) + (l & 15);
        float v = (col < 64) ? a_w1[k * 64 + col] : a_w1[(256 + k) * 64 + (col - 64)];
        Bsw2[o] = f2bf(v);
    } else if (idx < 66560) {                // a_w2 [64][16] -> 1ct x 2kc
        int o = idx - 65536;
        int j = o & 7, l = (o >> 3) & 63, kc = o >> 9;
        int k = kc * 32 + ((l >> 4) << 3) + j, col = l & 15;
        w2sw[o] = f2bf(a_w2[k * 16 + col]);
    }
}

// ---------------- gemm1: h_bf[N,256] = bf16( x[N,128] @ fc_w ) --------------------
// swapped mfma(B,A,acc) -> lane holds 4 contiguous output cols of one row
__global__ __launch_bounds__(256) void gemm1_kernel(const float* __restrict__ x,
    const u16* __restrict__ Bsw, u16* __restrict__ hb)
{
    const int tid = threadIdx.x, w = tid >> 6, l = tid & 63;
    const int lk = l >> 4;
    const int row = blockIdx.x * 64 + w * 16 + (l & 15);
    const int arow = row < NN ? row : NN - 1;
    const float* ap = x + (size_t)arow * INF + lk * 8;
    bf8 a[4];
#pragma unroll
    for (int kc = 0; kc < 4; ++kc) {
        float4 f0 = *(const float4*)(ap + kc * 32);
        float4 f1 = *(const float4*)(ap + kc * 32 + 4);
        bf8 t;
        t[0] = (short)f2bf(f0.x); t[1] = (short)f2bf(f0.y);
        t[2] = (short)f2bf(f0.z); t[3] = (short)f2bf(f0.w);
        t[4] = (short)f2bf(f1.x); t[5] = (short)f2bf(f1.y);
        t[6] = (short)f2bf(f1.z); t[7] = (short)f2bf(f1.w);
        a[kc] = t;
    }
    const bool ok = row < NN;
#pragma unroll
    for (int ct = 0; ct < 16; ct += 2) {
        f4 acc0 = {0.f, 0.f, 0.f, 0.f}, acc1 = {0.f, 0.f, 0.f, 0.f};
#pragma unroll
        for (int kc = 0; kc < 4; ++kc) {
            bf8 b0 = *(const bf8*)(Bsw + (((ct * 4 + kc) * 64 + l) << 3));
            bf8 b1 = *(const bf8*)(Bsw + ((((ct + 1) * 4 + kc) * 64 + l) << 3));
            acc0 = __builtin_amdgcn_mfma_f32_16x16x32_bf16(b0, a[kc], acc0, 0, 0, 0);
            acc1 = __builtin_amdgcn_mfma_f32_16x16x32_bf16(b1, a[kc], acc1, 0, 0, 0);
        }
        if (ok) {
            unsigned p0 = (unsigned)f2bf(acc0[0]) | ((unsigned)f2bf(acc0[1]) << 16);
            unsigned p1 = (unsigned)f2bf(acc0[2]) | ((unsigned)f2bf(acc0[3]) << 16);
            *(uint2*)(hb + (size_t)row * HD + ct * 16 + lk * 4) = make_uint2(p0, p1);
            unsigned p2 = (unsigned)f2bf(acc1[0]) | ((unsigned)f2bf(acc1[1]) << 16);
            unsigned p3 = (unsigned)f2bf(acc1[2]) | ((unsigned)f2bf(acc1[3]) << 16);
            *(uint2*)(hb + (size_t)row * HD + (ct + 1) * 16 + lk * 4) = make_uint2(p2, p3);
        }
    }
}

// ---------------- gemm2: pq_bf[N,128] = bf16( rst_bf @ [w1_top|w1_bot] + [0|b1] ) -
__global__ __launch_bounds__(256) void gemm2_kernel(const u16* __restrict__ rstb,
    const u16* __restrict__ Bsw, const float* __restrict__ a_b1, u16* __restrict__ pqb)
{
    const int tid = threadIdx.x, w = tid >> 6, l = tid & 63;
    const int lk = l >> 4;
    const int row = blockIdx.x * 64 + w * 16 + (l & 15);
    const int arow = row < NN ? row : NN - 1;
    const u16* ap = rstb + (size_t)arow * HD + lk * 8;
    bf8 a[8];
#pragma unroll
    for (int kc = 0; kc < 8; ++kc) a[kc] = *(const bf8*)(ap + kc * 32);
    const bool ok = row < NN;
#pragma unroll
    for (int ct = 0; ct < 8; ct += 2) {
        f4 acc0 = {0.f, 0.f, 0.f, 0.f}, acc1 = {0.f, 0.f, 0.f, 0.f};
#pragma unroll
        for (int kc = 0; kc < 8; ++kc) {
            bf8 b0 = *(const bf8*)(Bsw + (((ct * 8 + kc) * 64 + l) << 3));
            bf8 b1 = *(const bf8*)(Bsw + ((((ct + 1) * 8 + kc) * 64 + l) << 3));
            acc0 = __builtin_amdgcn_mfma_f32_16x16x32_bf16(b0, a[kc], acc0, 0, 0, 0);
            acc1 = __builtin_amdgcn_mfma_f32_16x16x32_bf16(b1, a[kc], acc1, 0, 0, 0);
        }
        if (ok) {
            const int c0 = ct * 16 + lk * 4;          // acc0 cols c0..c0+3, acc1 += 16
            float v0[4] = {acc0[0], acc0[1], acc0[2], acc0[3]};
            float v1[4] = {acc1[0], acc1[1], acc1[2], acc1[3]};
            if (c0 >= 64) {                           // q half: fold in b1
                float4 b = *(const float4*)(a_b1 + c0 - 64);
                v0[0] += b.x; v0[1] += b.y; v0[2] += b.z; v0[3] += b.w;
            }
            if (c0 + 16 >= 64) {
                float4 b = *(const float4*)(a_b1 + c0 + 16 - 64);
                v1[0] += b.x; v1[1] += b.y; v1[2] += b.z; v1[3] += b.w;
            }
            unsigned p0 = (unsigned)f2bf(v0[0]) | ((unsigned)f2bf(v0[1]) << 16);
            unsigned p1 = (unsigned)f2bf(v0[2]) | ((unsigned)f2bf(v0[3]) << 16);
            *(uint2*)(pqb + (size_t)row * 128 + c0) = make_uint2(p0, p1);
            unsigned p2 = (unsigned)f2bf(v1[0]) | ((unsigned)f2bf(v1[1]) << 16);
            unsigned p3 = (unsigned)f2bf(v1[2]) | ((unsigned)f2bf(v1[3]) << 16);
            *(uint2*)(pqb + (size_t)row * 128 + c0 + 16) = make_uint2(p2, p3);
        }
    }
}

// ---------------- el/er from bf16 h ----------------------------------------------
__global__ __launch_bounds__(128) void elr_kernel(const u16* __restrict__ hb,
    const float* __restrict__ attn_l, const float* __restrict__ attn_r,
    float* __restrict__ elr)
{
    const int n = blockIdx.x, t = threadIdx.x;
    const unsigned u = *(const unsigned*)(hb + (size_t)n * HD + 2 * t);
    const float v0 = bf2f((u16)u), v1 = bf2f((u16)(u >> 16));
    float l = v0 * attn_l[2 * t] + v1 * attn_l[2 * t + 1];
    float r = v0 * attn_r[2 * t] + v1 * attn_r[2 * t + 1];
#pragma unroll
    for (int off = 16; off; off >>= 1) { l += __shfl_xor(l, off); r += __shfl_xor(r, off); }
    if ((t & 31) == 0) {
        const int h = t >> 5;
        elr[(size_t)n * 8 + h] = l;
        elr[(size_t)n * 8 + 4 + h] = r;
    }
}

// ---------------- CSR build ------------------------------------------------------
__global__ __launch_bounds__(256) void deg_kernel(const int* __restrict__ dst,
                                                  int* __restrict__ deg)
{
    const int e = blockIdx.x * 256 + threadIdx.x;
    if (e < NE) atomicAdd(&deg[dst[e]], 1);
}

__global__ __launch_bounds__(256) void scan_block_kernel(const int* __restrict__ deg,
    int* __restrict__ excl, int* __restrict__ blocksum)
{
    __shared__ int tmp[256];
    const int t = threadIdx.x;
    const int i = blockIdx.x * 256 + t;
    const int v = (i < NN) ? deg[i] : 0;
    tmp[t] = v;
    __syncthreads();
    for (int off = 1; off < 256; off <<= 1) {
        int x = (t >= off) ? tmp[t - off] : 0;
        __syncthreads();
        tmp[t] += x;
        __syncthreads();
    }
    if (i < NN) excl[i] = tmp[t] - v;
    if (t == 255) blocksum[blockIdx.x] = tmp[255];
}

__global__ void scan_top_kernel(int* __restrict__ blocksum, int nb)
{
    const int lane = threadIdx.x;   // 64 threads
    int carry = 0;
    for (int base = 0; base < nb; base += 64) {
        const int i = base + lane;
        const int v = (i < nb) ? blocksum[i] : 0;
        int incl = v;
#pragma unroll
        for (int off = 1; off < 64; off <<= 1) {
            int x = __shfl_up(incl, off);
            if (lane >= off) incl += x;
        }
        if (i < nb) blocksum[i] = carry + incl - v;
        carry += __shfl(incl, 63);
    }
}

__global__ __launch_bounds__(256) void scan_add_kernel(const int* __restrict__ excl,
    const int* __restrict__ blocksum, int* __restrict__ rowptr, int* __restrict__ wptr)
{
    const int i = blockIdx.x * 256 + threadIdx.x;
    if (i < NN) {
        const int v = excl[i] + blocksum[blockIdx.x];
        rowptr[i] = v;
        wptr[i] = v;
    }
    if (i == 0) rowptr[NN] = NE;
}

__global__ __launch_bounds__(256) void scatter_kernel(const int* __restrict__ src,
    const int* __restrict__ dst, int* __restrict__ wptr, int* __restrict__ esrc)
{
    const int e = blockIdx.x * 256 + threadIdx.x;
    if (e < NE) {
        const int p = atomicAdd(&wptr[dst[e]], 1);
        esrc[p] = src[e];
    }
}

// ---------------- aggregation: 2-phase (ex once into LDS, then gather-FMA) --------
__global__ __launch_bounds__(128) void aggregate_kernel(
    const int* __restrict__ rowptr, const int* __restrict__ esrc,
    const float* __restrict__ elr, const u16* __restrict__ hb,
    const float* __restrict__ gat_bias, u16* __restrict__ rstb)
{
    __shared__ float exs[128];
    __shared__ int ssrc[32];
    const int d = blockIdx.x, t = threadIdx.x;
    const int h = t >> 5;                 // head owning features 2t,2t+1
    const int start = rowptr[d], end = rowptr[d + 1];
    const int p1j = t >> 2, p1h = t & 3;  // phase-1 task: edge p1j, head p1h
    const float erd = elr[(size_t)d * 8 + 4 + p1h];
    float acc0 = 0.f, acc1 = 0.f, zsum = 0.f;
    for (int cs = start; cs < end; cs += 32) {
        const int n = min(32, end - cs);
        __syncthreads();
        if (p1j < n) {
            const int s = esrc[cs + p1j];
            if (p1h == 0) ssrc[p1j] = s;
            float xv = elr[(size_t)s * 8 + p1h] + erd;
            xv = xv > 0.f ? xv : NEG_SLOPE * xv;
            exs[p1j * 4 + p1h] = expf(xv);
        }
        __syncthreads();
        for (int jj = 0; jj < n; ++jj) {
            const int s2 = ssrc[jj];
            const float e = exs[jj * 4 + h];
            zsum += e;
            const unsigned u = *(const unsigned*)(hb + (size_t)s2 * HD + 2 * t);
            acc0 += e * bf2f((u16)u);
            acc1 += e * bf2f((u16)(u >> 16));
        }
    }
    const float inv = (end > start) ? 1.f / zsum : 0.f;
    float v0 = acc0 * inv + gat_bias[2 * t];
    float v1 = acc1 * inv + gat_bias[2 * t + 1];
    v0 = v0 > 0.f ? v0 : expm1f(v0);
    v1 = v1 > 0.f ? v1 : expm1f(v1);
    const unsigned pk = (unsigned)f2bf(v0) | ((unsigned)f2bf(v1) << 16);
    *(unsigned*)(rstb + (size_t)d * HD + 2 * t) = pk;
}

// ---------------- column sums for graph mean --------------------------------------
__global__ __launch_bounds__(128) void mean_kernel(const u16* __restrict__ rstb,
                                                   float* __restrict__ gacc)
{
    const int t = threadIdx.x;
    float s0 = 0.f, s1 = 0.f;
    for (int n = blockIdx.x; n < NN; n += gridDim.x) {
        const unsigned u = *(const unsigned*)(rstb + (size_t)n * HD + 2 * t);
        s0 += bf2f((u16)u);
        s1 += bf2f((u16)(u >> 16));
    }
    atomicAdd(gacc + 2 * t, s0);
    atomicAdd(gacc + 2 * t + 1, s1);
}

// ---------------- edge MLP via MFMA: out[16e,16a] = relu(p[s]+q[d]) @ W2 + b2 -----
__global__ __launch_bounds__(256) void edge_mlp_kernel(const int* __restrict__ src,
    const int* __restrict__ dst, const u16* __restrict__ pq,
    const u16* __restrict__ w2sw, const float* __restrict__ a_b2,
    float* __restrict__ out)
{
    const int tid = threadIdx.x, w = tid >> 6, l = tid & 63;
    const int lk = l >> 4;
    const int e = blockIdx.x * 64 + w * 16 + (l & 15);
    const int s = src[e], d = dst[e];
    bf8 tf[2];
#pragma unroll
    for (int kc = 0; kc < 2; ++kc) {
        const int f = kc * 32 + lk * 8;
        bf8 pu = *(const bf8*)(pq + (size_t)s * 128 + f);
        bf8 qu = *(const bf8*)(pq + (size_t)d * 128 + 64 + f);
        bf8 t;
#pragma unroll
        for (int j = 0; j < 8; ++j) {
            float v = bf2f((u16)pu[j]) + bf2f((u16)qu[j]);   // b1 already folded into q
            v = fmaxf(v, 0.f);
            t[j] = (short)f2bf(v);
        }
        tf[kc] = t;
    }
    const float4 b2v = *(const float4*)(a_b2 + lk * 4);
    f4 acc = {b2v.x, b2v.y, b2v.z, b2v.w};
    const bf8 w0 = *(const bf8*)(w2sw + (l << 3));
    const bf8 w1 = *(const bf8*)(w2sw + ((64 + l) << 3));
    acc = __builtin_amdgcn_mfma_f32_16x16x32_bf16(w0, tf[0], acc, 0, 0, 0);
    acc = __builtin_amdgcn_mfma_f32_16x16x32_bf16(w1, tf[1], acc, 0, 0, 0);
    *(float4*)(out + (size_t)e * 16 + lk * 4) = make_float4(acc[0], acc[1], acc[2], acc[3]);
}

// ---------------- critic ---------------------------------------------------------
__global__ __launch_bounds__(256) void critic_kernel(const float* __restrict__ gacc,
    const float* __restrict__ c_w1, const float* __restrict__ c_b1,
    const float* __restrict__ c_w2, const float* __restrict__ c_b2,
    float* __restrict__ out)
{
    __shared__ float g[HD];
    __shared__ float t1[HID];
    const int t = threadIdx.x;
    g[t] = gacc[t] * (1.0f / (float)NN);
    __syncthreads();
    if (t < HID) {
        float s = c_b1[t];
        for (int c = 0; c < HD; ++c) s += g[c] * c_w1[c * HID + t];
        t1[t] = fmaxf(s, 0.f);
    }
    __syncthreads();
    if (t == 0) {
        float s = c_b2[0];
        for (int j = 0; j < HID; ++j) s += t1[j] * c_w2[j];
        out[0] = s;
    }
}

extern "C" void kernel_launch(void* const* d_in, const int* in_sizes, int n_in,
                              void* d_out, int out_size, void* d_ws, size_t ws_size,
                              hipStream_t stream)
{
    const float* x      = (const float*)d_in[0];
    const int*   src    = (const int*)d_in[1];
    const int*   dst    = (const int*)d_in[2];
    const float* fc_w   = (const float*)d_in[3];
    const float* attn_l = (const float*)d_in[4];
    const float* attn_r = (const float*)d_in[5];
    const float* gat_b  = (const float*)d_in[6];
    const float* a_w1   = (const float*)d_in[7];
    const float* a_b1   = (const float*)d_in[8];
    const float* a_w2   = (const float*)d_in[9];
    const float* a_b2   = (const float*)d_in[10];
    const float* c_w1   = (const float*)d_in[11];
    const float* c_b1   = (const float*)d_in[12];
    const float* c_w2   = (const float*)d_in[13];
    const float* c_b2   = (const float*)d_in[14];
    float* out = (float*)d_out;

    char* p = (char*)d_ws;
    u16* hb     = (u16*)p;  p += (size_t)NN * HD * 2;     // 25.6 MB
    u16* rstb   = (u16*)p;  p += (size_t)NN * HD * 2;     // 25.6 MB
    u16* pqb    = (u16*)p;  p += (size_t)NN * 128 * 2;    // 12.8 MB
    float* elr  = (float*)p; p += (size_t)NN * 8 * 4;     //  1.6 MB
    float* gacc = (float*)p; p += 1024;
    u16* Bsw1   = (u16*)p;  p += 65536;
    u16* Bsw2   = (u16*)p;  p += 65536;
    u16* w2sw   = (u16*)p;  p += 2048;
    int* deg      = (int*)p; p += (size_t)NN * 4;
    int* excl     = (int*)p; p += (size_t)NN * 4;
    int* blocksum = (int*)p; p += 1024;
    int* rowptr   = (int*)p; p += (size_t)(NN + 4) * 4;
    int* wptr     = (int*)p; p += (size_t)NN * 4;
    int* esrc     = (int*)p; p += (size_t)NE * 4;

    hipMemsetAsync(deg,  0, (size_t)NN * 4, stream);
    hipMemsetAsync(gacc, 0, 1024, stream);

    dim3 blk(256);
    const int NB = (NN + 255) / 256;  // 196
    // CSR build
    deg_kernel<<<dim3(3125), blk, 0, stream>>>(dst, deg);
    scan_block_kernel<<<dim3(NB), blk, 0, stream>>>(deg, excl, blocksum);
    scan_top_kernel<<<dim3(1), dim3(64), 0, stream>>>(blocksum, NB);
    scan_add_kernel<<<dim3(NB), blk, 0, stream>>>(excl, blocksum, rowptr, wptr);
    scatter_kernel<<<dim3(3125), blk, 0, stream>>>(src, dst, wptr, esrc);
    // weights -> swizzled bf16
    convw_kernel<<<dim3(260), blk, 0, stream>>>(fc_w, a_w1, a_w2, Bsw1, Bsw2, w2sw);
    // h = bf16(x @ fc_w)
    gemm1_kernel<<<dim3(782), blk, 0, stream>>>(x, Bsw1, hb);
    elr_kernel<<<dim3(NN), dim3(128), 0, stream>>>(hb, attn_l, attn_r, elr);
    aggregate_kernel<<<dim3(NN), dim3(128), 0, stream>>>(rowptr, esrc, elr, hb, gat_b, rstb);
    mean_kernel<<<dim3(512), dim3(128), 0, stream>>>(rstb, gacc);
    // pq = bf16(rst @ [w1_top | w1_bot] + [0 | b1])
    gemm2_kernel<<<dim3(782), blk, 0, stream>>>(rstb, Bsw2, a_b1, pqb);
    edge_mlp_kernel<<<dim3(NE / 64), blk, 0, stream>>>(src, dst, pqb, w2sw, a_b2, out);
    critic_kernel<<<dim3(1), blk, 0, stream>>>(gacc, c_w1, c_b1, c_w2, c_b2,
                                               out + (size_t)NE * ACT);
}